// Round 8
// baseline (212.360 us; speedup 1.0000x reference)
//
#include <hip/hip_runtime.h>
#include <hip/hip_bf16.h>

// out[t,l] = sum_{ijk} p1[t,i] p2[t,j] p3[t,k] grid[i,j,k,l]
// GEMM M=16384, K=4096 (k=i*256+j*16+kk), N=768; A built in registers.
// v7: revert to v5 2-buffer structure; BN 192->128 => LDS 36,864 B =>
//     3 blocks/CU resident (3 waves/SIMD). Split k_tr / k_prep for visibility.

using short8 = __attribute__((ext_vector_type(8))) short;
using f32x2  = __attribute__((ext_vector_type(2))) float;
using f32x4  = __attribute__((ext_vector_type(4))) float;
using f32x16 = __attribute__((ext_vector_type(16))) float;
using half8  = __attribute__((ext_vector_type(8))) _Float16;
using half2v = __attribute__((ext_vector_type(2))) _Float16;
typedef unsigned short ushort_t;
typedef unsigned int uint_t;

typedef const __attribute__((address_space(1))) void* gptr_t;
typedef __attribute__((address_space(3))) void* lptr_t;

#define PSTRIDE 52            // p row stride (floats)

static __device__ __forceinline__ ushort_t f2h_bits(float x) {
  union { _Float16 h; ushort_t u; } c;
  c.h = (_Float16)x;          // RNE
  return c.u;
}

// packed f32x2 -> f16x2 (RTZ), bit-cast to _Float16 vector
static __device__ __forceinline__ half2v cvt_pkrtz2(float a, float b) {
  auto r = __builtin_amdgcn_cvt_pkrtz(a, b);
  union { decltype(r) i; half2v o; } u;
  u.i = r;
  return u.o;
}

// ---------------------------------------------------------------------------
// Kernel 1: grid (4096 x 768 f32) -> gT (768 x 4096 f16)
// ---------------------------------------------------------------------------
__global__ __launch_bounds__(256) void k_tr(const float* __restrict__ g,
                                            ushort_t* __restrict__ gT) {
  __shared__ ushort_t tile[64][65];
  const int tx = threadIdx.x;
  const int r0 = blockIdx.x * 64;   // ijk base
  const int c0 = blockIdx.y * 64;   // l base
#pragma unroll
  for (int it = 0; it < 4; ++it) {
    const int idx = tx + it * 256;
    const int r = idx >> 4;
    const int c = (idx & 15) << 2;
    const float4 v = *(const float4*)(g + (size_t)(r0 + r) * 768 + (c0 + c));
    tile[c + 0][r] = f2h_bits(v.x);
    tile[c + 1][r] = f2h_bits(v.y);
    tile[c + 2][r] = f2h_bits(v.z);
    tile[c + 3][r] = f2h_bits(v.w);
  }
  __syncthreads();
#pragma unroll
  for (int it = 0; it < 4; ++it) {
    const int idx = tx + it * 256;
    const int r = idx >> 4;
    const int c = (idx & 15) << 2;
    ushort4 o;
    o.x = tile[r][c + 0]; o.y = tile[r][c + 1];
    o.z = tile[r][c + 2]; o.w = tile[r][c + 3];
    *(ushort4*)(gT + (size_t)(c0 + r) * 4096 + (r0 + c)) = o;
  }
}

// ---------------------------------------------------------------------------
// Kernel 2: p[t][48] = softmax16((x@W + b)/temp), three 16-groups.
// 512 thr = 8 waves; 64 tokens/block; x staged in LDS (coalesced, dbuf);
// wave wv handles d-slice wv*12..+12 of each 96-d chunk. Tree reduce.
// ---------------------------------------------------------------------------
__global__ __launch_bounds__(512) void k_prep(const float* __restrict__ x,
                                              const float* __restrict__ W1, const float* __restrict__ b1,
                                              const float* __restrict__ W2, const float* __restrict__ b2,
                                              const float* __restrict__ W3, const float* __restrict__ b3,
                                              const float* __restrict__ temp,
                                              float* __restrict__ p) {
  __shared__ union SmT {
    float x2[2][64][100];                   // 51,200 B
    float partial[4][64][PSTRIDE];          // 53,248 B
  } sm;
  const int tid = threadIdx.x;
  const int lane = tid & 63;
  const int wv = __builtin_amdgcn_readfirstlane(tid >> 6);  // 0..7 = d-slice
  const int t0 = blockIdx.x * 64;

  float acc[48];
#pragma unroll
  for (int q = 0; q < 48; ++q) acc[q] = 0.f;
  f32x2* a2 = (f32x2*)acc;

  const float* xbase = x + (size_t)t0 * 768;
  auto load_chunk = [&](int c, int b) {
#pragma unroll
    for (int it = 0; it < 3; ++it) {
      const int q = tid + it * 512;         // 0..1535
      const int r = q / 24;
      const int c4 = q % 24;
      const float4 v = *(const float4*)(xbase + (size_t)r * 768 + c * 96 + c4 * 4);
      *(float4*)&sm.x2[b][r][c4 * 4] = v;
    }
  };

  load_chunk(0, 0);
  __syncthreads();
  for (int c = 0; c < 8; ++c) {
    const int cur = c & 1;
    if (c < 7) load_chunk(c + 1, cur ^ 1);
    float xv[12];
#pragma unroll
    for (int rr = 0; rr < 3; ++rr) {
      const f32x4 v = *(const f32x4*)&sm.x2[cur][lane][wv * 12 + rr * 4];
      xv[rr * 4 + 0] = v[0]; xv[rr * 4 + 1] = v[1];
      xv[rr * 4 + 2] = v[2]; xv[rr * 4 + 3] = v[3];
    }
#pragma unroll
    for (int dd = 0; dd < 12; ++dd) {
      const int d = c * 96 + wv * 12 + dd;
      const float xs = xv[dd];
      const f32x2 xs2 = {xs, xs};
      const f32x2* w1r = (const f32x2*)(W1 + d * 16);
      const f32x2* w2r = (const f32x2*)(W2 + d * 16);
      const f32x2* w3r = (const f32x2*)(W3 + d * 16);
#pragma unroll
      for (int gg = 0; gg < 8; ++gg) {
        a2[gg]      = __builtin_elementwise_fma(xs2, w1r[gg], a2[gg]);
        a2[8 + gg]  = __builtin_elementwise_fma(xs2, w2r[gg], a2[8 + gg]);
        a2[16 + gg] = __builtin_elementwise_fma(xs2, w3r[gg], a2[16 + gg]);
      }
    }
    __syncthreads();
  }

  // tree reduce 8 -> 4 -> 2 -> 1
  if (wv >= 4) {
    f32x4* dst = (f32x4*)sm.partial[wv - 4][lane];
#pragma unroll
    for (int q = 0; q < 12; ++q) dst[q] = *(const f32x4*)&acc[q * 4];
  }
  __syncthreads();
  if (wv < 4) {
    const f32x4* src = (const f32x4*)sm.partial[wv][lane];
#pragma unroll
    for (int q = 0; q < 12; ++q) {
      const f32x4 v = src[q];
#pragma unroll
      for (int e = 0; e < 4; ++e) acc[q * 4 + e] += v[e];
    }
  }
  __syncthreads();
  if (wv == 2 || wv == 3) {
    f32x4* dst = (f32x4*)sm.partial[wv - 2][lane];
#pragma unroll
    for (int q = 0; q < 12; ++q) dst[q] = *(const f32x4*)&acc[q * 4];
  }
  __syncthreads();
  if (wv < 2) {
    const f32x4* src = (const f32x4*)sm.partial[wv][lane];
#pragma unroll
    for (int q = 0; q < 12; ++q) {
      const f32x4 v = src[q];
#pragma unroll
      for (int e = 0; e < 4; ++e) acc[q * 4 + e] += v[e];
    }
  }
  __syncthreads();
  if (wv == 1) {
    f32x4* dst = (f32x4*)sm.partial[0][lane];
#pragma unroll
    for (int q = 0; q < 12; ++q) dst[q] = *(const f32x4*)&acc[q * 4];
  }
  __syncthreads();
  if (wv == 0) {
    const f32x4* src = (const f32x4*)sm.partial[0][lane];
#pragma unroll
    for (int q = 0; q < 12; ++q) {
      const f32x4 v = src[q];
#pragma unroll
      for (int e = 0; e < 4; ++e) acc[q * 4 + e] += v[e];
    }
    const float invT = 1.0f / temp[0];
    float* prow = p + (size_t)(t0 + lane) * PSTRIDE;
#pragma unroll
    for (int grp = 0; grp < 3; ++grp) {
      const float* bias = (grp == 0) ? b1 : (grp == 1) ? b2 : b3;
      float z[16];
      float m = -3.0e38f;
#pragma unroll
      for (int q = 0; q < 16; ++q) {
        z[q] = (acc[grp * 16 + q] + bias[q]) * invT;
        m = fmaxf(m, z[q]);
      }
      float s = 0.f;
#pragma unroll
      for (int q = 0; q < 16; ++q) { z[q] = __expf(z[q] - m); s += z[q]; }
      const float rs = 1.0f / s;
#pragma unroll
      for (int q = 0; q < 16; ++q) prow[grp * 16 + q] = z[q] * rs;
    }
  }
}

// ---------------------------------------------------------------------------
// GEMM. BM=128 BN=128 BK=64; 4 waves 2x2, wave tile 64x64,
// v_mfma_f32_32x32x16_f16. v5 2-buffer structure (ds_reads -> stage ->
// setprio MFMA clusters -> vmcnt(0) -> barrier). LDS 36,864 B => 3 blk/CU.
// ---------------------------------------------------------------------------
__global__ __launch_bounds__(256, 4) void k_gemm(const float* __restrict__ p_g,
                                                 const ushort_t* __restrict__ gT,
                                                 float* __restrict__ out) {
  __shared__ ushort_t Bt[2][128 * 64];        // 32,768 B
  __shared__ ushort_t p1h[16 * 128];          //  4,096 B

  const int tid = threadIdx.x;
  const int lane = tid & 63;
  const int wv = __builtin_amdgcn_readfirstlane(tid >> 6);
  const int wm = wv >> 1, wn = wv & 1;
  const int g = lane >> 5;                    // k-half 0/1
  const int l31 = lane & 31;

  // XCD-aware swizzle over 768 blocks (768 % 8 == 0 -> bijective)
  const int f = blockIdx.y * 128 + blockIdx.x;
  const int w = (f & 7) * 96 + (f >> 3);
  const int m0 = (w & 127) * 128;
  const int n0 = (w >> 7) * 128;

  // p1h[i][row] cooperative build (f16)
  if (tid < 128) {
    const float* pr = p_g + (size_t)(m0 + tid) * PSTRIDE;
#pragma unroll
    for (int qq = 0; qq < 4; ++qq) {
      const f32x4 v = *(const f32x4*)(pr + qq * 4);
#pragma unroll
      for (int e = 0; e < 4; ++e) p1h[(qq * 4 + e) * 128 + tid] = f2h_bits(v[e]);
    }
  }

  // per-lane p2 (16 f16-broadcast pairs) and p3 (own k-half, 8 f32) per m-rep
  const int rowA0 = m0 + wm * 64 + l31;
  half2v p2h[2][16];
  float p3r[2][8];
#pragma unroll
  for (int mr = 0; mr < 2; ++mr) {
    const float* pr = p_g + (size_t)(rowA0 + mr * 32) * PSTRIDE;
#pragma unroll
    for (int qq = 0; qq < 4; ++qq) {
      const f32x4 v = *(const f32x4*)(pr + 16 + qq * 4);
#pragma unroll
      for (int e = 0; e < 4; ++e)
        p2h[mr][qq * 4 + e] = cvt_pkrtz2(v[e], v[e]);
    }
#pragma unroll
    for (int qq = 0; qq < 2; ++qq) {
      const f32x4 v = *(const f32x4*)(pr + 32 + 8 * g + qq * 4);
      p3r[mr][qq * 4 + 0] = v[0]; p3r[mr][qq * 4 + 1] = v[1];
      p3r[mr][qq * 4 + 2] = v[2]; p3r[mr][qq * 4 + 3] = v[3];
    }
  }

  // B staging: linear LDS dest + inverse-swizzled source (16B chunks)
  const int srow = wv * 32 + (lane >> 3);
  const int schunk = (lane & 7) ^ (lane >> 3);
  const ushort_t* sbase = gT + (size_t)(n0 + srow) * 4096 + schunk * 8;
  auto stage = [&](int buf, int kt) {
    const ushort_t* src = sbase + kt * 64;
#pragma unroll
    for (int q = 0; q < 4; ++q) {
      __builtin_amdgcn_global_load_lds((gptr_t)(src + (size_t)q * 8 * 4096),
                                       (lptr_t)&Bt[buf][(wv * 32 + q * 8) * 64], 16, 0, 0);
    }
  };

  f32x16 acc[2][2];
#pragma unroll
  for (int mr = 0; mr < 2; ++mr)
#pragma unroll
    for (int nf = 0; nf < 2; ++nf)
#pragma unroll
      for (int e = 0; e < 16; ++e) acc[mr][nf][e] = 0.f;

  stage(0, 0);
  asm volatile("s_waitcnt vmcnt(0) lgkmcnt(0)" ::: "memory");
  __builtin_amdgcn_s_barrier();

  const int rowLoc0 = wm * 64 + l31;
  for (int io = 0; io < 16; ++io) {           // i-index (p1)
    half2v p1p3h[2][4];
#pragma unroll
    for (int mr = 0; mr < 2; ++mr) {
      union { ushort_t u; _Float16 h; } c;
      c.u = p1h[io * 128 + rowLoc0 + mr * 32];
      const float p1v = (float)c.h;
#pragma unroll
      for (int q = 0; q < 4; ++q)
        p1p3h[mr][q] = cvt_pkrtz2(p1v * p3r[mr][2 * q],
                                  p1v * p3r[mr][2 * q + 1]);
    }
#pragma unroll
    for (int kq = 0; kq < 4; ++kq) {
      const int kt = io * 4 + kq;
      const ushort_t* bbuf = Bt[kq & 1];

      // issue all 8 B-fragment reads up front (counted lgkm waits)
      half8 b[4][2];
#pragma unroll
      for (int s = 0; s < 4; ++s) {
        const int cd = 2 * s + g;
#pragma unroll
        for (int nf = 0; nf < 2; ++nf) {
          const int r = wn * 64 + nf * 32 + l31;
          b[s][nf] = *(const half8*)&bbuf[r * 64 + ((cd ^ (r & 7)) << 3)];
        }
      }
      // prefetch next K64 tile
      if (kq < 3 || io < 15) stage((kq + 1) & 1, kt + 1);

#pragma unroll
      for (int s = 0; s < 4; ++s) {
        const int j = kq * 4 + s;             // static p2 index
        half8 a[2];
#pragma unroll
        for (int mr = 0; mr < 2; ++mr) {
          union { half2v h2[4]; half8 h8; } pk;
#pragma unroll
          for (int q = 0; q < 4; ++q) pk.h2[q] = p2h[mr][j] * p1p3h[mr][q];
          a[mr] = pk.h8;
        }
        __builtin_amdgcn_s_setprio(1);
#pragma unroll
        for (int mr = 0; mr < 2; ++mr)
#pragma unroll
          for (int nf = 0; nf < 2; ++nf)
            acc[mr][nf] = __builtin_amdgcn_mfma_f32_32x32x16_f16(a[mr], b[s][nf], acc[mr][nf], 0, 0, 0);
        __builtin_amdgcn_s_setprio(0);
      }
      asm volatile("s_waitcnt vmcnt(0)" ::: "memory");
      __builtin_amdgcn_s_barrier();
    }
  }

  // epilogue: 32x32 C/D: col = lane&31, row = (reg&3)+8*(reg>>2)+4*(lane>>5)
#pragma unroll
  for (int mr = 0; mr < 2; ++mr)
#pragma unroll
    for (int nf = 0; nf < 2; ++nf)
#pragma unroll
      for (int reg = 0; reg < 16; ++reg) {
        const int row = (reg & 3) + 8 * (reg >> 2) + 4 * g;
        const int t = m0 + wm * 64 + mr * 32 + row;
        out[(size_t)t * 768 + n0 + wn * 64 + nf * 32 + l31] = acc[mr][nf][reg];
      }
}

// ---------------------------------------------------------------------------
extern "C" void kernel_launch(void* const* d_in, const int* in_sizes, int n_in,
                              void* d_out, int out_size, void* d_ws, size_t ws_size,
                              hipStream_t stream) {
  (void)in_sizes; (void)n_in; (void)out_size; (void)ws_size;
  const float* x    = (const float*)d_in[0];
  const float* W1   = (const float*)d_in[1];
  const float* b1   = (const float*)d_in[2];
  const float* W2   = (const float*)d_in[3];
  const float* b2   = (const float*)d_in[4];
  const float* W3   = (const float*)d_in[5];
  const float* b3   = (const float*)d_in[6];
  const float* grid = (const float*)d_in[7];
  const float* temp = (const float*)d_in[8];
  float* out = (float*)d_out;

  // ws: gT f16 [768][4096] = 6,291,456 B ; p f32 [16384][52] = 3,407,872 B
  ushort_t* gT = (ushort_t*)d_ws;
  float* p = (float*)((char*)d_ws + 6291456);

  k_tr<<<dim3(64, 12), 256, 0, stream>>>(grid, gT);
  k_prep<<<dim3(256), 512, 0, stream>>>(x, W1, b1, W2, b2, W3, b3, temp, p);
  k_gemm<<<dim3(128, 6), 256, 0, stream>>>(p, gT, out);
}

// Round 9
// 177.223 us; speedup vs baseline: 1.1983x; 1.1983x over previous
//
#include <hip/hip_runtime.h>
#include <hip/hip_bf16.h>

// out[t,l] = sum_{ijk} p1[t,i] p2[t,j] p3[t,k] grid[i,j,k,l]
// GEMM M=16384, K=4096 (k=i*256+j*16+kk), N=768; A built in registers.
// v8: 4-buffer LDS pipeline, STATIC buffer indices (kt%4 == kq literal),
//     stage(kt+3) issued first, counted vmcnt(8) (never 0 in loop).
//     BN=128 (acc 64), no VGPR cap.

using short8 = __attribute__((ext_vector_type(8))) short;
using f32x2  = __attribute__((ext_vector_type(2))) float;
using f32x4  = __attribute__((ext_vector_type(4))) float;
using f32x16 = __attribute__((ext_vector_type(16))) float;
using half8  = __attribute__((ext_vector_type(8))) _Float16;
using half2v = __attribute__((ext_vector_type(2))) _Float16;
typedef unsigned short ushort_t;
typedef unsigned int uint_t;

typedef const __attribute__((address_space(1))) void* gptr_t;
typedef __attribute__((address_space(3))) void* lptr_t;

#define PSTRIDE 52            // p row stride (floats)

static __device__ __forceinline__ ushort_t f2h_bits(float x) {
  union { _Float16 h; ushort_t u; } c;
  c.h = (_Float16)x;          // RNE
  return c.u;
}

// packed f32x2 -> f16x2 (RTZ), bit-cast to _Float16 vector
static __device__ __forceinline__ half2v cvt_pkrtz2(float a, float b) {
  auto r = __builtin_amdgcn_cvt_pkrtz(a, b);
  union { decltype(r) i; half2v o; } u;
  u.i = r;
  return u.o;
}

// ---------------------------------------------------------------------------
// Kernel 1: grid (4096 x 768 f32) -> gT (768 x 4096 f16)
// ---------------------------------------------------------------------------
__global__ __launch_bounds__(256) void k_tr(const float* __restrict__ g,
                                            ushort_t* __restrict__ gT) {
  __shared__ ushort_t tile[64][65];
  const int tx = threadIdx.x;
  const int r0 = blockIdx.x * 64;   // ijk base
  const int c0 = blockIdx.y * 64;   // l base
#pragma unroll
  for (int it = 0; it < 4; ++it) {
    const int idx = tx + it * 256;
    const int r = idx >> 4;
    const int c = (idx & 15) << 2;
    const float4 v = *(const float4*)(g + (size_t)(r0 + r) * 768 + (c0 + c));
    tile[c + 0][r] = f2h_bits(v.x);
    tile[c + 1][r] = f2h_bits(v.y);
    tile[c + 2][r] = f2h_bits(v.z);
    tile[c + 3][r] = f2h_bits(v.w);
  }
  __syncthreads();
#pragma unroll
  for (int it = 0; it < 4; ++it) {
    const int idx = tx + it * 256;
    const int r = idx >> 4;
    const int c = (idx & 15) << 2;
    ushort4 o;
    o.x = tile[r][c + 0]; o.y = tile[r][c + 1];
    o.z = tile[r][c + 2]; o.w = tile[r][c + 3];
    *(ushort4*)(gT + (size_t)(c0 + r) * 4096 + (r0 + c)) = o;
  }
}

// ---------------------------------------------------------------------------
// Kernel 2: p[t][48] = softmax16((x@W + b)/temp), three 16-groups.
// 512 thr = 8 waves; 64 tokens/block; x staged in LDS (coalesced, dbuf);
// wave wv handles d-slice wv*12..+12 of each 96-d chunk. Tree reduce.
// ---------------------------------------------------------------------------
__global__ __launch_bounds__(512) void k_prep(const float* __restrict__ x,
                                              const float* __restrict__ W1, const float* __restrict__ b1,
                                              const float* __restrict__ W2, const float* __restrict__ b2,
                                              const float* __restrict__ W3, const float* __restrict__ b3,
                                              const float* __restrict__ temp,
                                              float* __restrict__ p) {
  __shared__ union SmT {
    float x2[2][64][100];                   // 51,200 B
    float partial[4][64][PSTRIDE];          // 53,248 B
  } sm;
  const int tid = threadIdx.x;
  const int lane = tid & 63;
  const int wv = __builtin_amdgcn_readfirstlane(tid >> 6);  // 0..7 = d-slice
  const int t0 = blockIdx.x * 64;

  float acc[48];
#pragma unroll
  for (int q = 0; q < 48; ++q) acc[q] = 0.f;
  f32x2* a2 = (f32x2*)acc;

  const float* xbase = x + (size_t)t0 * 768;
  auto load_chunk = [&](int c, int b) {
#pragma unroll
    for (int it = 0; it < 3; ++it) {
      const int q = tid + it * 512;         // 0..1535
      const int r = q / 24;
      const int c4 = q % 24;
      const float4 v = *(const float4*)(xbase + (size_t)r * 768 + c * 96 + c4 * 4);
      *(float4*)&sm.x2[b][r][c4 * 4] = v;
    }
  };

  load_chunk(0, 0);
  __syncthreads();
  for (int c = 0; c < 8; ++c) {
    const int cur = c & 1;
    if (c < 7) load_chunk(c + 1, cur ^ 1);
    float xv[12];
#pragma unroll
    for (int rr = 0; rr < 3; ++rr) {
      const f32x4 v = *(const f32x4*)&sm.x2[cur][lane][wv * 12 + rr * 4];
      xv[rr * 4 + 0] = v[0]; xv[rr * 4 + 1] = v[1];
      xv[rr * 4 + 2] = v[2]; xv[rr * 4 + 3] = v[3];
    }
#pragma unroll
    for (int dd = 0; dd < 12; ++dd) {
      const int d = c * 96 + wv * 12 + dd;
      const float xs = xv[dd];
      const f32x2 xs2 = {xs, xs};
      const f32x2* w1r = (const f32x2*)(W1 + d * 16);
      const f32x2* w2r = (const f32x2*)(W2 + d * 16);
      const f32x2* w3r = (const f32x2*)(W3 + d * 16);
#pragma unroll
      for (int gg = 0; gg < 8; ++gg) {
        a2[gg]      = __builtin_elementwise_fma(xs2, w1r[gg], a2[gg]);
        a2[8 + gg]  = __builtin_elementwise_fma(xs2, w2r[gg], a2[8 + gg]);
        a2[16 + gg] = __builtin_elementwise_fma(xs2, w3r[gg], a2[16 + gg]);
      }
    }
    __syncthreads();
  }

  // tree reduce 8 -> 4 -> 2 -> 1
  if (wv >= 4) {
    f32x4* dst = (f32x4*)sm.partial[wv - 4][lane];
#pragma unroll
    for (int q = 0; q < 12; ++q) dst[q] = *(const f32x4*)&acc[q * 4];
  }
  __syncthreads();
  if (wv < 4) {
    const f32x4* src = (const f32x4*)sm.partial[wv][lane];
#pragma unroll
    for (int q = 0; q < 12; ++q) {
      const f32x4 v = src[q];
#pragma unroll
      for (int e = 0; e < 4; ++e) acc[q * 4 + e] += v[e];
    }
  }
  __syncthreads();
  if (wv == 2 || wv == 3) {
    f32x4* dst = (f32x4*)sm.partial[wv - 2][lane];
#pragma unroll
    for (int q = 0; q < 12; ++q) dst[q] = *(const f32x4*)&acc[q * 4];
  }
  __syncthreads();
  if (wv < 2) {
    const f32x4* src = (const f32x4*)sm.partial[wv][lane];
#pragma unroll
    for (int q = 0; q < 12; ++q) {
      const f32x4 v = src[q];
#pragma unroll
      for (int e = 0; e < 4; ++e) acc[q * 4 + e] += v[e];
    }
  }
  __syncthreads();
  if (wv == 1) {
    f32x4* dst = (f32x4*)sm.partial[0][lane];
#pragma unroll
    for (int q = 0; q < 12; ++q) dst[q] = *(const f32x4*)&acc[q * 4];
  }
  __syncthreads();
  if (wv == 0) {
    const f32x4* src = (const f32x4*)sm.partial[0][lane];
#pragma unroll
    for (int q = 0; q < 12; ++q) {
      const f32x4 v = src[q];
#pragma unroll
      for (int e = 0; e < 4; ++e) acc[q * 4 + e] += v[e];
    }
    const float invT = 1.0f / temp[0];
    float* prow = p + (size_t)(t0 + lane) * PSTRIDE;
#pragma unroll
    for (int grp = 0; grp < 3; ++grp) {
      const float* bias = (grp == 0) ? b1 : (grp == 1) ? b2 : b3;
      float z[16];
      float m = -3.0e38f;
#pragma unroll
      for (int q = 0; q < 16; ++q) {
        z[q] = (acc[grp * 16 + q] + bias[q]) * invT;
        m = fmaxf(m, z[q]);
      }
      float s = 0.f;
#pragma unroll
      for (int q = 0; q < 16; ++q) { z[q] = __expf(z[q] - m); s += z[q]; }
      const float rs = 1.0f / s;
#pragma unroll
      for (int q = 0; q < 16; ++q) prow[grp * 16 + q] = z[q] * rs;
    }
  }
}

// ---------------------------------------------------------------------------
// GEMM. BM=128 BN=128 BK=64; 4 waves 2x2, wave tile 64x64,
// v_mfma_f32_32x32x16_f16. 4-buffer pipeline, STATIC buf index (kt%4==kq),
// stage(kt+3) first in body, end-of-kt s_waitcnt vmcnt(8) (tile kt+1 landed,
// kt+2/kt+3 still flying). Barrier per kt protects buffer reuse (distance 3,
// last read 2 barriers earlier for stage target... buf (kt+3)%4 last read at
// kt-1, one barrier back -> all waves past their reads).  LDS 69,632 B.
// ---------------------------------------------------------------------------
__global__ __launch_bounds__(256, 2) void k_gemm(const float* __restrict__ p_g,
                                                 const ushort_t* __restrict__ gT,
                                                 float* __restrict__ out) {
  __shared__ ushort_t Bt[4][128 * 64];        // 65,536 B
  __shared__ ushort_t p1h[16 * 128];          //  4,096 B

  const int tid = threadIdx.x;
  const int lane = tid & 63;
  const int wv = __builtin_amdgcn_readfirstlane(tid >> 6);
  const int wm = wv >> 1, wn = wv & 1;
  const int g = lane >> 5;                    // k-half 0/1
  const int l31 = lane & 31;

  // XCD-aware swizzle over 768 blocks (768 % 8 == 0 -> bijective)
  const int f = blockIdx.y * 128 + blockIdx.x;
  const int w = (f & 7) * 96 + (f >> 3);
  const int m0 = (w & 127) * 128;
  const int n0 = (w >> 7) * 128;

  // p1h[i][row] cooperative build (f16)
  if (tid < 128) {
    const float* pr = p_g + (size_t)(m0 + tid) * PSTRIDE;
#pragma unroll
    for (int qq = 0; qq < 4; ++qq) {
      const f32x4 v = *(const f32x4*)(pr + qq * 4);
#pragma unroll
      for (int e = 0; e < 4; ++e) p1h[(qq * 4 + e) * 128 + tid] = f2h_bits(v[e]);
    }
  }

  // per-lane p2 (16 f16-broadcast pairs) and p3 (own k-half, 8 f32) per m-rep
  const int rowA0 = m0 + wm * 64 + l31;
  half2v p2h[2][16];
  float p3r[2][8];
#pragma unroll
  for (int mr = 0; mr < 2; ++mr) {
    const float* pr = p_g + (size_t)(rowA0 + mr * 32) * PSTRIDE;
#pragma unroll
    for (int qq = 0; qq < 4; ++qq) {
      const f32x4 v = *(const f32x4*)(pr + 16 + qq * 4);
#pragma unroll
      for (int e = 0; e < 4; ++e)
        p2h[mr][qq * 4 + e] = cvt_pkrtz2(v[e], v[e]);
    }
#pragma unroll
    for (int qq = 0; qq < 2; ++qq) {
      const f32x4 v = *(const f32x4*)(pr + 32 + 8 * g + qq * 4);
      p3r[mr][qq * 4 + 0] = v[0]; p3r[mr][qq * 4 + 1] = v[1];
      p3r[mr][qq * 4 + 2] = v[2]; p3r[mr][qq * 4 + 3] = v[3];
    }
  }

  // B staging: linear LDS dest + inverse-swizzled source (16B chunks)
  const int srow = wv * 32 + (lane >> 3);
  const int schunk = (lane & 7) ^ (lane >> 3);
  const ushort_t* sbase = gT + (size_t)(n0 + srow) * 4096 + schunk * 8;
  auto stage = [&](int buf, int kt) {
    const ushort_t* src = sbase + kt * 64;
#pragma unroll
    for (int q = 0; q < 4; ++q) {
      __builtin_amdgcn_global_load_lds((gptr_t)(src + (size_t)q * 8 * 4096),
                                       (lptr_t)&Bt[buf][(wv * 32 + q * 8) * 64], 16, 0, 0);
    }
  };

  f32x16 acc[2][2];
#pragma unroll
  for (int mr = 0; mr < 2; ++mr)
#pragma unroll
    for (int nf = 0; nf < 2; ++nf)
#pragma unroll
      for (int e = 0; e < 16; ++e) acc[mr][nf][e] = 0.f;

  // drain p-traffic (global reads + LDS writes) before counted staging
  asm volatile("s_waitcnt vmcnt(0) lgkmcnt(0)" ::: "memory");
  __builtin_amdgcn_s_barrier();

  stage(0, 0);
  stage(1, 1);
  stage(2, 2);
  asm volatile("s_waitcnt vmcnt(8)" ::: "memory");  // tile 0 landed
  __builtin_amdgcn_s_barrier();

  const int rowLoc0 = wm * 64 + l31;
  for (int io = 0; io < 16; ++io) {           // i-index (p1)
    half2v p1p3h[2][4];
#pragma unroll
    for (int mr = 0; mr < 2; ++mr) {
      union { ushort_t u; _Float16 h; } c;
      c.u = p1h[io * 128 + rowLoc0 + mr * 32];
      const float p1v = (float)c.h;
#pragma unroll
      for (int q = 0; q < 4; ++q)
        p1p3h[mr][q] = cvt_pkrtz2(p1v * p3r[mr][2 * q],
                                  p1v * p3r[mr][2 * q + 1]);
    }
#pragma unroll
    for (int kq = 0; kq < 4; ++kq) {          // kt%4 == kq (static buffers)
      const int kt = io * 4 + kq;
      // stage tile kt+3 into buf (kq+3)&3 FIRST -> ~3 kt of flight time
      if (kt < 61) stage((kq + 3) & 3, kt + 3);

      const ushort_t* bbuf = Bt[kq];          // static LDS base
      half8 b[4][2];
#pragma unroll
      for (int s = 0; s < 4; ++s) {
        const int cd = 2 * s + g;
#pragma unroll
        for (int nf = 0; nf < 2; ++nf) {
          const int r = wn * 64 + nf * 32 + l31;
          b[s][nf] = *(const half8*)&bbuf[r * 64 + ((cd ^ (r & 7)) << 3)];
        }
      }

#pragma unroll
      for (int s = 0; s < 4; ++s) {
        const int j = kq * 4 + s;             // static p2 index
        half8 a[2];
#pragma unroll
        for (int mr = 0; mr < 2; ++mr) {
          union { half2v h2[4]; half8 h8; } pk;
#pragma unroll
          for (int q = 0; q < 4; ++q) pk.h2[q] = p2h[mr][j] * p1p3h[mr][q];
          a[mr] = pk.h8;
        }
        __builtin_amdgcn_s_setprio(1);
#pragma unroll
        for (int mr = 0; mr < 2; ++mr)
#pragma unroll
          for (int nf = 0; nf < 2; ++nf)
            acc[mr][nf] = __builtin_amdgcn_mfma_f32_32x32x16_f16(a[mr], b[s][nf], acc[mr][nf], 0, 0, 0);
        __builtin_amdgcn_s_setprio(0);
      }

      // counted wait: tile kt+1 resident; kt+2 / kt+3 stay in flight
      if (kt < 61) {
        asm volatile("s_waitcnt vmcnt(8)" ::: "memory");
      } else if (kt == 61) {
        asm volatile("s_waitcnt vmcnt(4)" ::: "memory");
      } else if (kt == 62) {
        asm volatile("s_waitcnt vmcnt(0)" ::: "memory");
      }
      if (kt < 63) __builtin_amdgcn_s_barrier();
    }
  }

  // epilogue: 32x32 C/D: col = lane&31, row = (reg&3)+8*(reg>>2)+4*(lane>>5)
#pragma unroll
  for (int mr = 0; mr < 2; ++mr)
#pragma unroll
    for (int nf = 0; nf < 2; ++nf)
#pragma unroll
      for (int reg = 0; reg < 16; ++reg) {
        const int row = (reg & 3) + 8 * (reg >> 2) + 4 * g;
        const int t = m0 + wm * 64 + mr * 32 + row;
        out[(size_t)t * 768 + n0 + wn * 64 + nf * 32 + l31] = acc[mr][nf][reg];
      }
}

// ---------------------------------------------------------------------------
extern "C" void kernel_launch(void* const* d_in, const int* in_sizes, int n_in,
                              void* d_out, int out_size, void* d_ws, size_t ws_size,
                              hipStream_t stream) {
  (void)in_sizes; (void)n_in; (void)out_size; (void)ws_size;
  const float* x    = (const float*)d_in[0];
  const float* W1   = (const float*)d_in[1];
  const float* b1   = (const float*)d_in[2];
  const float* W2   = (const float*)d_in[3];
  const float* b2   = (const float*)d_in[4];
  const float* W3   = (const float*)d_in[5];
  const float* b3   = (const float*)d_in[6];
  const float* grid = (const float*)d_in[7];
  const float* temp = (const float*)d_in[8];
  float* out = (float*)d_out;

  // ws: gT f16 [768][4096] = 6,291,456 B ; p f32 [16384][52] = 3,407,872 B
  ushort_t* gT = (ushort_t*)d_ws;
  float* p = (float*)((char*)d_ws + 6291456);

  k_tr<<<dim3(64, 12), 256, 0, stream>>>(grid, gT);
  k_prep<<<dim3(256), 512, 0, stream>>>(x, W1, b1, W2, b2, W3, b3, temp, p);
  k_gemm<<<dim3(128, 6), 256, 0, stream>>>(p, gT, out);
}

// Round 10
// 171.588 us; speedup vs baseline: 1.2376x; 1.0328x over previous
//
#include <hip/hip_runtime.h>
#include <hip/hip_bf16.h>

// out[t,l] = sum_{ijk} p1[t,i] p2[t,j] p3[t,k] grid[i,j,k,l]
// GEMM M=16384, K=4096 (k=i*256+j*16+kk), N=768; A built in registers.
// v9: BARRIER-FREE K-loop. BM=64 BN=128, 4 waves 1x4 (wave tile 64x32,
//     mr=2, nf=1). Each wave stages ONLY the 32 B-rows it reads into its
//     private double-buffered LDS region -> own vmcnt orders DMA vs ds_read,
//     no __syncthreads in loop. Group-padded LDS (8 rows + 32B) kills the
//     4-way bank conflict. Grid 1536 blocks (clean multiple of 512).

using f32x2  = __attribute__((ext_vector_type(2))) float;
using f32x4  = __attribute__((ext_vector_type(4))) float;
using f32x16 = __attribute__((ext_vector_type(16))) float;
using half8  = __attribute__((ext_vector_type(8))) _Float16;
using half2v = __attribute__((ext_vector_type(2))) _Float16;
typedef unsigned short ushort_t;
typedef unsigned int uint_t;

typedef const __attribute__((address_space(1))) void* gptr_t;
typedef __attribute__((address_space(3))) void* lptr_t;

#define PSTRIDE 52            // p row stride (floats)

static __device__ __forceinline__ ushort_t f2h_bits(float x) {
  union { _Float16 h; ushort_t u; } c;
  c.h = (_Float16)x;          // RNE
  return c.u;
}

static __device__ __forceinline__ half2v cvt_pkrtz2(float a, float b) {
  auto r = __builtin_amdgcn_cvt_pkrtz(a, b);
  union { decltype(r) i; half2v o; } u;
  u.i = r;
  return u.o;
}

// ---------------------------------------------------------------------------
// Kernel 1: grid (4096 x 768 f32) -> gT (768 x 4096 f16)
// ---------------------------------------------------------------------------
__global__ __launch_bounds__(256) void k_tr(const float* __restrict__ g,
                                            ushort_t* __restrict__ gT) {
  __shared__ ushort_t tile[64][65];
  const int tx = threadIdx.x;
  const int r0 = blockIdx.x * 64;   // ijk base
  const int c0 = blockIdx.y * 64;   // l base
#pragma unroll
  for (int it = 0; it < 4; ++it) {
    const int idx = tx + it * 256;
    const int r = idx >> 4;
    const int c = (idx & 15) << 2;
    const float4 v = *(const float4*)(g + (size_t)(r0 + r) * 768 + (c0 + c));
    tile[c + 0][r] = f2h_bits(v.x);
    tile[c + 1][r] = f2h_bits(v.y);
    tile[c + 2][r] = f2h_bits(v.z);
    tile[c + 3][r] = f2h_bits(v.w);
  }
  __syncthreads();
#pragma unroll
  for (int it = 0; it < 4; ++it) {
    const int idx = tx + it * 256;
    const int r = idx >> 4;
    const int c = (idx & 15) << 2;
    ushort4 o;
    o.x = tile[r][c + 0]; o.y = tile[r][c + 1];
    o.z = tile[r][c + 2]; o.w = tile[r][c + 3];
    *(ushort4*)(gT + (size_t)(c0 + r) * 4096 + (r0 + c)) = o;
  }
}

// ---------------------------------------------------------------------------
// Kernel 2: p[t][48] = softmax16((x@W + b)/temp)  (unchanged from v7)
// ---------------------------------------------------------------------------
__global__ __launch_bounds__(512) void k_prep(const float* __restrict__ x,
                                              const float* __restrict__ W1, const float* __restrict__ b1,
                                              const float* __restrict__ W2, const float* __restrict__ b2,
                                              const float* __restrict__ W3, const float* __restrict__ b3,
                                              const float* __restrict__ temp,
                                              float* __restrict__ p) {
  __shared__ union SmT {
    float x2[2][64][100];                   // 51,200 B
    float partial[4][64][PSTRIDE];          // 53,248 B
  } sm;
  const int tid = threadIdx.x;
  const int lane = tid & 63;
  const int wv = __builtin_amdgcn_readfirstlane(tid >> 6);  // 0..7 = d-slice
  const int t0 = blockIdx.x * 64;

  float acc[48];
#pragma unroll
  for (int q = 0; q < 48; ++q) acc[q] = 0.f;
  f32x2* a2 = (f32x2*)acc;

  const float* xbase = x + (size_t)t0 * 768;
  auto load_chunk = [&](int c, int b) {
#pragma unroll
    for (int it = 0; it < 3; ++it) {
      const int q = tid + it * 512;         // 0..1535
      const int r = q / 24;
      const int c4 = q % 24;
      const float4 v = *(const float4*)(xbase + (size_t)r * 768 + c * 96 + c4 * 4);
      *(float4*)&sm.x2[b][r][c4 * 4] = v;
    }
  };

  load_chunk(0, 0);
  __syncthreads();
  for (int c = 0; c < 8; ++c) {
    const int cur = c & 1;
    if (c < 7) load_chunk(c + 1, cur ^ 1);
    float xv[12];
#pragma unroll
    for (int rr = 0; rr < 3; ++rr) {
      const f32x4 v = *(const f32x4*)&sm.x2[cur][lane][wv * 12 + rr * 4];
      xv[rr * 4 + 0] = v[0]; xv[rr * 4 + 1] = v[1];
      xv[rr * 4 + 2] = v[2]; xv[rr * 4 + 3] = v[3];
    }
#pragma unroll
    for (int dd = 0; dd < 12; ++dd) {
      const int d = c * 96 + wv * 12 + dd;
      const float xs = xv[dd];
      const f32x2 xs2 = {xs, xs};
      const f32x2* w1r = (const f32x2*)(W1 + d * 16);
      const f32x2* w2r = (const f32x2*)(W2 + d * 16);
      const f32x2* w3r = (const f32x2*)(W3 + d * 16);
#pragma unroll
      for (int gg = 0; gg < 8; ++gg) {
        a2[gg]      = __builtin_elementwise_fma(xs2, w1r[gg], a2[gg]);
        a2[8 + gg]  = __builtin_elementwise_fma(xs2, w2r[gg], a2[8 + gg]);
        a2[16 + gg] = __builtin_elementwise_fma(xs2, w3r[gg], a2[16 + gg]);
      }
    }
    __syncthreads();
  }

  // tree reduce 8 -> 4 -> 2 -> 1
  if (wv >= 4) {
    f32x4* dst = (f32x4*)sm.partial[wv - 4][lane];
#pragma unroll
    for (int q = 0; q < 12; ++q) dst[q] = *(const f32x4*)&acc[q * 4];
  }
  __syncthreads();
  if (wv < 4) {
    const f32x4* src = (const f32x4*)sm.partial[wv][lane];
#pragma unroll
    for (int q = 0; q < 12; ++q) {
      const f32x4 v = src[q];
#pragma unroll
      for (int e = 0; e < 4; ++e) acc[q * 4 + e] += v[e];
    }
  }
  __syncthreads();
  if (wv == 2 || wv == 3) {
    f32x4* dst = (f32x4*)sm.partial[wv - 2][lane];
#pragma unroll
    for (int q = 0; q < 12; ++q) dst[q] = *(const f32x4*)&acc[q * 4];
  }
  __syncthreads();
  if (wv < 2) {
    const f32x4* src = (const f32x4*)sm.partial[wv][lane];
#pragma unroll
    for (int q = 0; q < 12; ++q) {
      const f32x4 v = src[q];
#pragma unroll
      for (int e = 0; e < 4; ++e) acc[q * 4 + e] += v[e];
    }
  }
  __syncthreads();
  if (wv == 1) {
    f32x4* dst = (f32x4*)sm.partial[0][lane];
#pragma unroll
    for (int q = 0; q < 12; ++q) dst[q] = *(const f32x4*)&acc[q * 4];
  }
  __syncthreads();
  if (wv == 0) {
    const f32x4* src = (const f32x4*)sm.partial[0][lane];
#pragma unroll
    for (int q = 0; q < 12; ++q) {
      const f32x4 v = src[q];
#pragma unroll
      for (int e = 0; e < 4; ++e) acc[q * 4 + e] += v[e];
    }
    const float invT = 1.0f / temp[0];
    float* prow = p + (size_t)(t0 + lane) * PSTRIDE;
#pragma unroll
    for (int grp = 0; grp < 3; ++grp) {
      const float* bias = (grp == 0) ? b1 : (grp == 1) ? b2 : b3;
      float z[16];
      float m = -3.0e38f;
#pragma unroll
      for (int q = 0; q < 16; ++q) {
        z[q] = (acc[grp * 16 + q] + bias[q]) * invT;
        m = fmaxf(m, z[q]);
      }
      float s = 0.f;
#pragma unroll
      for (int q = 0; q < 16; ++q) { z[q] = __expf(z[q] - m); s += z[q]; }
      const float rs = 1.0f / s;
#pragma unroll
      for (int q = 0; q < 16; ++q) prow[grp * 16 + q] = z[q] * rs;
    }
  }
}

// ---------------------------------------------------------------------------
// Kernel 3: barrier-free GEMM. Each wave owns n-slice [wv*32, wv*32+32):
// stages it privately (global_load_lds -> own LDS region, 2 bufs), reads it
// alone. Own vmcnt(4) counted wait per kt; NO __syncthreads in the K-loop.
// LDS region per wave-buf: 4 groups x (8 rows x 128B + 32B pad) = 4224 B;
// the per-group 32B pad rotates banks so the 4 lanes sharing a chunk-slot
// land on distinct banks (conflict-free reads).
// ---------------------------------------------------------------------------
__global__ __launch_bounds__(256) void k_gemm(const float* __restrict__ p_g,
                                              const ushort_t* __restrict__ gT,
                                              float* __restrict__ out) {
  __shared__ ushort_t Bt[4][2][2112];         // [wave][buf][4224 B] = 33,792 B
  __shared__ ushort_t p1h[16 * 64];           //  2,048 B

  const int tid = threadIdx.x;
  const int lane = tid & 63;
  const int wv = __builtin_amdgcn_readfirstlane(tid >> 6);
  const int g = lane >> 5;                    // k-half 0/1
  const int l31 = lane & 31;

  // XCD swizzle over 1536 blocks (1536 % 8 == 0 -> bijective)
  const int f = blockIdx.y * 256 + blockIdx.x;
  const int w = (f & 7) * 192 + (f >> 3);
  const int m0 = (w & 255) * 64;              // token base (64-row tile)
  const int n0 = (w >> 8) * 128;              // latent base

  // p1h[i*64+row] build (wave 0 threads)
  if (tid < 64) {
    const float* pr = p_g + (size_t)(m0 + tid) * PSTRIDE;
#pragma unroll
    for (int qq = 0; qq < 4; ++qq) {
      const f32x4 v = *(const f32x4*)(pr + qq * 4);
#pragma unroll
      for (int e = 0; e < 4; ++e) p1h[(qq * 4 + e) * 64 + tid] = f2h_bits(v[e]);
    }
  }

  // per-lane p2 (16 broadcast pairs) / p3 (own k-half) for rows l31, l31+32
  half2v p2h[2][16];
  float p3r[2][8];
#pragma unroll
  for (int mr = 0; mr < 2; ++mr) {
    const float* pr = p_g + (size_t)(m0 + mr * 32 + l31) * PSTRIDE;
#pragma unroll
    for (int qq = 0; qq < 4; ++qq) {
      const f32x4 v = *(const f32x4*)(pr + 16 + qq * 4);
#pragma unroll
      for (int e = 0; e < 4; ++e)
        p2h[mr][qq * 4 + e] = cvt_pkrtz2(v[e], v[e]);
    }
#pragma unroll
    for (int qq = 0; qq < 2; ++qq) {
      const f32x4 v = *(const f32x4*)(pr + 32 + 8 * g + qq * 4);
      p3r[mr][qq * 4 + 0] = v[0]; p3r[mr][qq * 4 + 1] = v[1];
      p3r[mr][qq * 4 + 2] = v[2]; p3r[mr][qq * 4 + 3] = v[3];
    }
  }

  // private staging: lane covers (row-in-group lq = lane>>3, slot = lane&7);
  // source chunk = slot ^ lq  (read slot = chunk ^ (row&7), same involution)
  const int lq = lane >> 3;
  const int schunk = (lane & 7) ^ lq;
  const ushort_t* sbase = gT + (size_t)(n0 + wv * 32 + lq) * 4096 + schunk * 8;
  auto stage = [&](int buf, int kt) {
    const ushort_t* src = sbase + kt * 64;
#pragma unroll
    for (int q = 0; q < 4; ++q) {
      __builtin_amdgcn_global_load_lds((gptr_t)(src + (size_t)q * 8 * 4096),
                                       (lptr_t)&Bt[wv][buf][q * 528], 16, 0, 0);
    }
  };

  f32x16 acc[2];
#pragma unroll
  for (int mr = 0; mr < 2; ++mr)
#pragma unroll
    for (int e = 0; e < 16; ++e) acc[mr][e] = 0.f;

  stage(0, 0);
  __syncthreads();                            // publish p1h (also drains stage 0)

  // per-lane LDS read base: group (l31>>3)*1056B + row (l31&7)*128B
  const int rbase = (l31 >> 3) * 528 + (l31 & 7) * 64;
  const int r7 = l31 & 7;

  for (int io = 0; io < 16; ++io) {           // i-index (p1)
    half2v p1p3h[2][4];
#pragma unroll
    for (int mr = 0; mr < 2; ++mr) {
      union { ushort_t u; _Float16 h; } c;
      c.u = p1h[io * 64 + mr * 32 + l31];
      const float p1v = (float)c.h;
#pragma unroll
      for (int q = 0; q < 4; ++q)
        p1p3h[mr][q] = cvt_pkrtz2(p1v * p3r[mr][2 * q],
                                  p1v * p3r[mr][2 * q + 1]);
    }
#pragma unroll
    for (int kq = 0; kq < 4; ++kq) {
      const int kt = io * 4 + kq;
      if (kt < 63) {
        stage((kt + 1) & 1, kt + 1);          // own prefetch, 1 kt ahead
        asm volatile("s_waitcnt vmcnt(4)" ::: "memory");  // kt's 4 landed
      } else {
        asm volatile("s_waitcnt vmcnt(0)" ::: "memory");
      }

      const ushort_t* bb = &Bt[wv][kt & 1][0];
      half8 b[4];
#pragma unroll
      for (int s = 0; s < 4; ++s) {
        const int slot = (2 * s + g) ^ r7;
        b[s] = *(const half8*)&bb[rbase + slot * 8];
      }

#pragma unroll
      for (int s = 0; s < 4; ++s) {
        const int j = kq * 4 + s;             // static p2 index
        half8 a[2];
#pragma unroll
        for (int mr = 0; mr < 2; ++mr) {
          union { half2v h2[4]; half8 h8; } pk;
#pragma unroll
          for (int q = 0; q < 4; ++q) pk.h2[q] = p2h[mr][j] * p1p3h[mr][q];
          a[mr] = pk.h8;
        }
        __builtin_amdgcn_s_setprio(1);
        acc[0] = __builtin_amdgcn_mfma_f32_32x32x16_f16(a[0], b[s], acc[0], 0, 0, 0);
        acc[1] = __builtin_amdgcn_mfma_f32_32x32x16_f16(a[1], b[s], acc[1], 0, 0, 0);
        __builtin_amdgcn_s_setprio(0);
      }
    }
  }

  // epilogue: 32x32 C/D: col = lane&31, row = (reg&3)+8*(reg>>2)+4*(lane>>5)
#pragma unroll
  for (int mr = 0; mr < 2; ++mr)
#pragma unroll
    for (int reg = 0; reg < 16; ++reg) {
      const int row = (reg & 3) + 8 * (reg >> 2) + 4 * g;
      const int t = m0 + mr * 32 + row;
      out[(size_t)t * 768 + n0 + wv * 32 + l31] = acc[mr][reg];
    }
}

// ---------------------------------------------------------------------------
extern "C" void kernel_launch(void* const* d_in, const int* in_sizes, int n_in,
                              void* d_out, int out_size, void* d_ws, size_t ws_size,
                              hipStream_t stream) {
  (void)in_sizes; (void)n_in; (void)out_size; (void)ws_size;
  const float* x    = (const float*)d_in[0];
  const float* W1   = (const float*)d_in[1];
  const float* b1   = (const float*)d_in[2];
  const float* W2   = (const float*)d_in[3];
  const float* b2   = (const float*)d_in[4];
  const float* W3   = (const float*)d_in[5];
  const float* b3   = (const float*)d_in[6];
  const float* grid = (const float*)d_in[7];
  const float* temp = (const float*)d_in[8];
  float* out = (float*)d_out;

  // ws: gT f16 [768][4096] = 6,291,456 B ; p f32 [16384][52] = 3,407,872 B
  ushort_t* gT = (ushort_t*)d_ws;
  float* p = (float*)((char*)d_ws + 6291456);

  k_tr<<<dim3(64, 12), 256, 0, stream>>>(grid, gT);
  k_prep<<<dim3(256), 512, 0, stream>>>(x, W1, b1, W2, b2, W3, b3, temp, p);
  k_gemm<<<dim3(256, 6), 256, 0, stream>>>(p, gT, out);
}

// Round 11
// 145.949 us; speedup vs baseline: 1.4550x; 1.1757x over previous
//
#include <hip/hip_runtime.h>
#include <hip/hip_bf16.h>

// out[t,l] = sum_{ijk} p1[t,i] p2[t,j] p3[t,k] grid[i,j,k,l]
// GEMM M=16384, K=4096 (k=i*256+j*16+kk), N=768; A built in registers.
// v10: fat-wave config. BM=256 BN=192, grid 64x4=256 blocks = 1/CU.
//      4 waves 2x2, wave tile 128x96 (mr=4, nf=3) -> 48 MFMA/kt/wave;
//      LDS reads halve per CU, B staging/L2 traffic halves. v5's proven
//      2-buffer drain schedule unchanged. ~350 VGPR -> 1 wave/SIMD.

using f32x2  = __attribute__((ext_vector_type(2))) float;
using f32x4  = __attribute__((ext_vector_type(4))) float;
using f32x16 = __attribute__((ext_vector_type(16))) float;
using half8  = __attribute__((ext_vector_type(8))) _Float16;
using half2v = __attribute__((ext_vector_type(2))) _Float16;
typedef unsigned short ushort_t;
typedef unsigned int uint_t;

typedef const __attribute__((address_space(1))) void* gptr_t;
typedef __attribute__((address_space(3))) void* lptr_t;

#define PSTRIDE 52            // p row stride (floats)

static __device__ __forceinline__ ushort_t f2h_bits(float x) {
  union { _Float16 h; ushort_t u; } c;
  c.h = (_Float16)x;          // RNE
  return c.u;
}

static __device__ __forceinline__ half2v cvt_pkrtz2(float a, float b) {
  auto r = __builtin_amdgcn_cvt_pkrtz(a, b);
  union { decltype(r) i; half2v o; } u;
  u.i = r;
  return u.o;
}

// ---------------------------------------------------------------------------
// Kernel 1: grid (4096 x 768 f32) -> gT (768 x 4096 f16)
// ---------------------------------------------------------------------------
__global__ __launch_bounds__(256) void k_tr(const float* __restrict__ g,
                                            ushort_t* __restrict__ gT) {
  __shared__ ushort_t tile[64][65];
  const int tx = threadIdx.x;
  const int r0 = blockIdx.x * 64;   // ijk base
  const int c0 = blockIdx.y * 64;   // l base
#pragma unroll
  for (int it = 0; it < 4; ++it) {
    const int idx = tx + it * 256;
    const int r = idx >> 4;
    const int c = (idx & 15) << 2;
    const float4 v = *(const float4*)(g + (size_t)(r0 + r) * 768 + (c0 + c));
    tile[c + 0][r] = f2h_bits(v.x);
    tile[c + 1][r] = f2h_bits(v.y);
    tile[c + 2][r] = f2h_bits(v.z);
    tile[c + 3][r] = f2h_bits(v.w);
  }
  __syncthreads();
#pragma unroll
  for (int it = 0; it < 4; ++it) {
    const int idx = tx + it * 256;
    const int r = idx >> 4;
    const int c = (idx & 15) << 2;
    ushort4 o;
    o.x = tile[r][c + 0]; o.y = tile[r][c + 1];
    o.z = tile[r][c + 2]; o.w = tile[r][c + 3];
    *(ushort4*)(gT + (size_t)(c0 + r) * 4096 + (r0 + c)) = o;
  }
}

// ---------------------------------------------------------------------------
// Kernel 2: p[t][48] = softmax16((x@W + b)/temp)  (unchanged)
// ---------------------------------------------------------------------------
__global__ __launch_bounds__(512) void k_prep(const float* __restrict__ x,
                                              const float* __restrict__ W1, const float* __restrict__ b1,
                                              const float* __restrict__ W2, const float* __restrict__ b2,
                                              const float* __restrict__ W3, const float* __restrict__ b3,
                                              const float* __restrict__ temp,
                                              float* __restrict__ p) {
  __shared__ union SmT {
    float x2[2][64][100];                   // 51,200 B
    float partial[4][64][PSTRIDE];          // 53,248 B
  } sm;
  const int tid = threadIdx.x;
  const int lane = tid & 63;
  const int wv = __builtin_amdgcn_readfirstlane(tid >> 6);  // 0..7 = d-slice
  const int t0 = blockIdx.x * 64;

  float acc[48];
#pragma unroll
  for (int q = 0; q < 48; ++q) acc[q] = 0.f;
  f32x2* a2 = (f32x2*)acc;

  const float* xbase = x + (size_t)t0 * 768;
  auto load_chunk = [&](int c, int b) {
#pragma unroll
    for (int it = 0; it < 3; ++it) {
      const int q = tid + it * 512;         // 0..1535
      const int r = q / 24;
      const int c4 = q % 24;
      const float4 v = *(const float4*)(xbase + (size_t)r * 768 + c * 96 + c4 * 4);
      *(float4*)&sm.x2[b][r][c4 * 4] = v;
    }
  };

  load_chunk(0, 0);
  __syncthreads();
  for (int c = 0; c < 8; ++c) {
    const int cur = c & 1;
    if (c < 7) load_chunk(c + 1, cur ^ 1);
    float xv[12];
#pragma unroll
    for (int rr = 0; rr < 3; ++rr) {
      const f32x4 v = *(const f32x4*)&sm.x2[cur][lane][wv * 12 + rr * 4];
      xv[rr * 4 + 0] = v[0]; xv[rr * 4 + 1] = v[1];
      xv[rr * 4 + 2] = v[2]; xv[rr * 4 + 3] = v[3];
    }
#pragma unroll
    for (int dd = 0; dd < 12; ++dd) {
      const int d = c * 96 + wv * 12 + dd;
      const float xs = xv[dd];
      const f32x2 xs2 = {xs, xs};
      const f32x2* w1r = (const f32x2*)(W1 + d * 16);
      const f32x2* w2r = (const f32x2*)(W2 + d * 16);
      const f32x2* w3r = (const f32x2*)(W3 + d * 16);
#pragma unroll
      for (int gg = 0; gg < 8; ++gg) {
        a2[gg]      = __builtin_elementwise_fma(xs2, w1r[gg], a2[gg]);
        a2[8 + gg]  = __builtin_elementwise_fma(xs2, w2r[gg], a2[8 + gg]);
        a2[16 + gg] = __builtin_elementwise_fma(xs2, w3r[gg], a2[16 + gg]);
      }
    }
    __syncthreads();
  }

  // tree reduce 8 -> 4 -> 2 -> 1
  if (wv >= 4) {
    f32x4* dst = (f32x4*)sm.partial[wv - 4][lane];
#pragma unroll
    for (int q = 0; q < 12; ++q) dst[q] = *(const f32x4*)&acc[q * 4];
  }
  __syncthreads();
  if (wv < 4) {
    const f32x4* src = (const f32x4*)sm.partial[wv][lane];
#pragma unroll
    for (int q = 0; q < 12; ++q) {
      const f32x4 v = src[q];
#pragma unroll
      for (int e = 0; e < 4; ++e) acc[q * 4 + e] += v[e];
    }
  }
  __syncthreads();
  if (wv == 2 || wv == 3) {
    f32x4* dst = (f32x4*)sm.partial[wv - 2][lane];
#pragma unroll
    for (int q = 0; q < 12; ++q) dst[q] = *(const f32x4*)&acc[q * 4];
  }
  __syncthreads();
  if (wv < 2) {
    const f32x4* src = (const f32x4*)sm.partial[wv][lane];
#pragma unroll
    for (int q = 0; q < 12; ++q) {
      const f32x4 v = src[q];
#pragma unroll
      for (int e = 0; e < 4; ++e) acc[q * 4 + e] += v[e];
    }
  }
  __syncthreads();
  if (wv == 1) {
    f32x4* dst = (f32x4*)sm.partial[0][lane];
#pragma unroll
    for (int q = 0; q < 12; ++q) dst[q] = *(const f32x4*)&acc[q * 4];
  }
  __syncthreads();
  if (wv == 0) {
    const f32x4* src = (const f32x4*)sm.partial[0][lane];
#pragma unroll
    for (int q = 0; q < 12; ++q) {
      const f32x4 v = src[q];
#pragma unroll
      for (int e = 0; e < 4; ++e) acc[q * 4 + e] += v[e];
    }
    const float invT = 1.0f / temp[0];
    float* prow = p + (size_t)(t0 + lane) * PSTRIDE;
#pragma unroll
    for (int grp = 0; grp < 3; ++grp) {
      const float* bias = (grp == 0) ? b1 : (grp == 1) ? b2 : b3;
      float z[16];
      float m = -3.0e38f;
#pragma unroll
      for (int q = 0; q < 16; ++q) {
        z[q] = (acc[grp * 16 + q] + bias[q]) * invT;
        m = fmaxf(m, z[q]);
      }
      float s = 0.f;
#pragma unroll
      for (int q = 0; q < 16; ++q) { z[q] = __expf(z[q] - m); s += z[q]; }
      const float rs = 1.0f / s;
#pragma unroll
      for (int q = 0; q < 16; ++q) prow[grp * 16 + q] = z[q] * rs;
    }
  }
}

// ---------------------------------------------------------------------------
// Kernel 3: GEMM. BM=256 BN=192 BK=64; 4 waves 2x2, wave tile 128x96
// (mr=4, nf=3, 48 MFMA/kt). v5 schedule: b-reads -> stage(kt+1) -> 4 setprio
// clusters of 12 MFMA -> vmcnt(0) -> barrier. 1 block/CU (grid 256).
// ---------------------------------------------------------------------------
__global__ __launch_bounds__(256, 1) void k_gemm(const float* __restrict__ p_g,
                                                 const ushort_t* __restrict__ gT,
                                                 float* __restrict__ out) {
  __shared__ ushort_t Bt[2][192 * 64];        // 49,152 B
  __shared__ ushort_t p1h[16 * 256];          //  8,192 B

  const int tid = threadIdx.x;
  const int lane = tid & 63;
  const int wv = __builtin_amdgcn_readfirstlane(tid >> 6);
  const int wm = wv >> 1, wn = wv & 1;
  const int g = lane >> 5;                    // k-half 0/1
  const int l31 = lane & 31;

  // XCD swizzle over 256 blocks (256 % 8 == 0 -> bijective)
  const int f = blockIdx.y * 64 + blockIdx.x;
  const int w = (f & 7) * 32 + (f >> 3);
  const int m0 = (w & 63) * 256;              // token base
  const int n0 = (w >> 6) * 192;              // latent base

  // p1h[i*256+row] build (all 256 threads, one row each)
  {
    const float* pr = p_g + (size_t)(m0 + tid) * PSTRIDE;
#pragma unroll
    for (int qq = 0; qq < 4; ++qq) {
      const f32x4 v = *(const f32x4*)(pr + qq * 4);
#pragma unroll
      for (int e = 0; e < 4; ++e) p1h[(qq * 4 + e) * 256 + tid] = f2h_bits(v[e]);
    }
  }

  // per-lane p2 (16 broadcast pairs) / p3 (own k-half) for 4 m-rep rows
  half2v p2h[4][16];
  float p3r[4][8];
#pragma unroll
  for (int mr = 0; mr < 4; ++mr) {
    const float* pr = p_g + (size_t)(m0 + wm * 128 + mr * 32 + l31) * PSTRIDE;
#pragma unroll
    for (int qq = 0; qq < 4; ++qq) {
      const f32x4 v = *(const f32x4*)(pr + 16 + qq * 4);
#pragma unroll
      for (int e = 0; e < 4; ++e)
        p2h[mr][qq * 4 + e] = cvt_pkrtz2(v[e], v[e]);
    }
#pragma unroll
    for (int qq = 0; qq < 2; ++qq) {
      const f32x4 v = *(const f32x4*)(pr + 32 + 8 * g + qq * 4);
      p3r[mr][qq * 4 + 0] = v[0]; p3r[mr][qq * 4 + 1] = v[1];
      p3r[mr][qq * 4 + 2] = v[2]; p3r[mr][qq * 4 + 3] = v[3];
    }
  }

  // B staging: wave covers 48 rows; linear LDS dest + inverse-swizzled source
  const int srow = wv * 48 + (lane >> 3);
  const int schunk = (lane & 7) ^ (lane >> 3);
  const ushort_t* sbase = gT + (size_t)(n0 + srow) * 4096 + schunk * 8;
  auto stage = [&](int buf, int kt) {
    const ushort_t* src = sbase + kt * 64;
#pragma unroll
    for (int q = 0; q < 6; ++q) {
      __builtin_amdgcn_global_load_lds((gptr_t)(src + (size_t)q * 8 * 4096),
                                       (lptr_t)&Bt[buf][(wv * 48 + q * 8) * 64], 16, 0, 0);
    }
  };

  f32x16 acc[4][3];
#pragma unroll
  for (int mr = 0; mr < 4; ++mr)
#pragma unroll
    for (int nf = 0; nf < 3; ++nf)
#pragma unroll
      for (int e = 0; e < 16; ++e) acc[mr][nf][e] = 0.f;

  stage(0, 0);
  asm volatile("s_waitcnt vmcnt(0) lgkmcnt(0)" ::: "memory");
  __builtin_amdgcn_s_barrier();

  for (int io = 0; io < 16; ++io) {           // i-index (p1)
    half2v p1p3h[4][4];
#pragma unroll
    for (int mr = 0; mr < 4; ++mr) {
      union { ushort_t u; _Float16 h; } c;
      c.u = p1h[io * 256 + wm * 128 + mr * 32 + l31];
      const float p1v = (float)c.h;
#pragma unroll
      for (int q = 0; q < 4; ++q)
        p1p3h[mr][q] = cvt_pkrtz2(p1v * p3r[mr][2 * q],
                                  p1v * p3r[mr][2 * q + 1]);
    }
#pragma unroll
    for (int kq = 0; kq < 4; ++kq) {
      const int kt = io * 4 + kq;
      const ushort_t* bbuf = Bt[kq & 1];

      // all 12 B-fragment reads up front (counted lgkm waits by compiler)
      half8 b[4][3];
#pragma unroll
      for (int s = 0; s < 4; ++s) {
        const int cd = 2 * s + g;
#pragma unroll
        for (int nf = 0; nf < 3; ++nf) {
          const int r = wn * 96 + nf * 32 + l31;
          b[s][nf] = *(const half8*)&bbuf[r * 64 + ((cd ^ (r & 7)) << 3)];
        }
      }
      // prefetch next K64 tile (whole MFMA phase to land)
      if (kt < 63) stage((kq + 1) & 1, kt + 1);

#pragma unroll
      for (int s = 0; s < 4; ++s) {
        const int j = kq * 4 + s;             // static p2 index
        half8 a[4];
#pragma unroll
        for (int mr = 0; mr < 4; ++mr) {
          union { half2v h2[4]; half8 h8; } pk;
#pragma unroll
          for (int q = 0; q < 4; ++q) pk.h2[q] = p2h[mr][j] * p1p3h[mr][q];
          a[mr] = pk.h8;
        }
        __builtin_amdgcn_s_setprio(1);
#pragma unroll
        for (int mr = 0; mr < 4; ++mr)
#pragma unroll
          for (int nf = 0; nf < 3; ++nf)
            acc[mr][nf] = __builtin_amdgcn_mfma_f32_32x32x16_f16(a[mr], b[s][nf], acc[mr][nf], 0, 0, 0);
        __builtin_amdgcn_s_setprio(0);
      }
      asm volatile("s_waitcnt vmcnt(0)" ::: "memory");
      __builtin_amdgcn_s_barrier();
    }
  }

  // epilogue: 32x32 C/D: col = lane&31, row = (reg&3)+8*(reg>>2)+4*(lane>>5)
#pragma unroll
  for (int mr = 0; mr < 4; ++mr)
#pragma unroll
    for (int nf = 0; nf < 3; ++nf)
#pragma unroll
      for (int reg = 0; reg < 16; ++reg) {
        const int row = (reg & 3) + 8 * (reg >> 2) + 4 * g;
        const int t = m0 + wm * 128 + mr * 32 + row;
        out[(size_t)t * 768 + n0 + wn * 96 + nf * 32 + l31] = acc[mr][nf][reg];
      }
}

// ---------------------------------------------------------------------------
extern "C" void kernel_launch(void* const* d_in, const int* in_sizes, int n_in,
                              void* d_out, int out_size, void* d_ws, size_t ws_size,
                              hipStream_t stream) {
  (void)in_sizes; (void)n_in; (void)out_size; (void)ws_size;
  const float* x    = (const float*)d_in[0];
  const float* W1   = (const float*)d_in[1];
  const float* b1   = (const float*)d_in[2];
  const float* W2   = (const float*)d_in[3];
  const float* b2   = (const float*)d_in[4];
  const float* W3   = (const float*)d_in[5];
  const float* b3   = (const float*)d_in[6];
  const float* grid = (const float*)d_in[7];
  const float* temp = (const float*)d_in[8];
  float* out = (float*)d_out;

  // ws: gT f16 [768][4096] = 6,291,456 B ; p f32 [16384][52] = 3,407,872 B
  ushort_t* gT = (ushort_t*)d_ws;
  float* p = (float*)((char*)d_ws + 6291456);

  k_tr<<<dim3(64, 12), 256, 0, stream>>>(grid, gT);
  k_prep<<<dim3(256), 512, 0, stream>>>(x, W1, b1, W2, b2, W3, b3, temp, p);
  k_gemm<<<dim3(64, 4), 256, 0, stream>>>(p, gT, out);
}